// Round 1
// baseline (207.125 us; speedup 1.0000x reference)
//
#include <hip/hip_runtime.h>
#include <hip/hip_bf16.h>
#include <cstdint>
#include <cstddef>

#define NN 10000
#define NE 160000
#define DD 300
#define KP 320      // K padded to 10 MFMA steps of 32
#define NPAD 304    // N (W rows) padded to 19 tiles of 16
#define NTILES 19

using bf16x8 = __attribute__((ext_vector_type(8))) __bf16;
using f32x4  = __attribute__((ext_vector_type(4))) float;

// ---------------- CSR build ----------------

__global__ void zero_i32(int* p, int n) {
    int i = blockIdx.x * 256 + threadIdx.x;
    if (i < n) p[i] = 0;
}

__global__ void hist_kernel(const int* __restrict__ dst, int* __restrict__ counts) {
    int e = blockIdx.x * 256 + threadIdx.x;
    if (e < NE) atomicAdd(&counts[dst[e]], 1);
}

// single-block exclusive scan over NN counts -> offsets[NN+1]
__global__ __launch_bounds__(1024) void scan_kernel(const int* __restrict__ counts,
                                                    int* __restrict__ offsets) {
    __shared__ int sm[1024];
    __shared__ int carry_s;
    if (threadIdx.x == 0) carry_s = 0;
    __syncthreads();
    for (int base = 0; base < NN; base += 1024) {
        int i = base + (int)threadIdx.x;
        int x = (i < NN) ? counts[i] : 0;
        sm[threadIdx.x] = x;
        __syncthreads();
        for (int off = 1; off < 1024; off <<= 1) {
            int v = (threadIdx.x >= (unsigned)off) ? sm[threadIdx.x - off] : 0;
            __syncthreads();
            sm[threadIdx.x] += v;
            __syncthreads();
        }
        int incl = sm[threadIdx.x];
        int carry = carry_s;
        if (i < NN) offsets[i] = carry + incl - x;   // exclusive
        __syncthreads();
        if (threadIdx.x == 1023) carry_s = carry + sm[1023];
        __syncthreads();
    }
    if (threadIdx.x == 0) offsets[NN] = carry_s;
}

__global__ void copy_i32(const int* __restrict__ s, int* __restrict__ d, int n) {
    int i = blockIdx.x * 256 + threadIdx.x;
    if (i < n) d[i] = s[i];
}

__global__ void scatter_kernel(const int* __restrict__ src, const int* __restrict__ dst,
                               int* __restrict__ cursor, int* __restrict__ esrc) {
    int e = blockIdx.x * 256 + threadIdx.x;
    if (e < NE) {
        int pos = atomicAdd(&cursor[dst[e]], 1);
        esrc[pos] = src[e];
    }
}

// ---------------- W -> bf16 padded [NPAD][KP] ----------------

__global__ void convw_kernel(const float* __restrict__ W, __bf16* __restrict__ Wb) {
    int idx = blockIdx.x * 256 + threadIdx.x;
    if (idx >= NPAD * KP) return;
    int n = idx / KP;
    int k = idx - n * KP;
    float v = (n < DD && k < DD) ? W[n * DD + k] : 0.f;
    Wb[idx] = (__bf16)v;
}

// ---------------- aggregation: wave per node, gather-sum, write bf16 padded ----------------

__global__ __launch_bounds__(256) void agg_kernel(const float* __restrict__ h,
                                                  __bf16* __restrict__ agg,
                                                  const int* __restrict__ offsets,
                                                  const int* __restrict__ esrc) {
    int node = (int)((blockIdx.x * 256 + threadIdx.x) >> 6);
    int lane = threadIdx.x & 63;
    if (node >= NN) return;
    const float* self_row = h + (size_t)node * DD;
    float acc[5];
#pragma unroll
    for (int i = 0; i < 5; ++i) {
        int d = lane + 64 * i;
        acc[i] = (d < DD) ? self_row[d] : 0.f;
    }
    int p0 = offsets[node], p1 = offsets[node + 1];
    for (int p = p0; p < p1; ++p) {
        const float* row = h + (size_t)esrc[p] * DD;
#pragma unroll
        for (int i = 0; i < 5; ++i) {
            int d = lane + 64 * i;
            if (d < DD) acc[i] += row[d];
        }
    }
    __bf16* o = agg + (size_t)node * KP;
#pragma unroll
    for (int i = 0; i < 5; ++i) {
        int d = lane + 64 * i;
        o[d] = (__bf16)acc[i];   // d>=300 stores 0 (pad)
    }
}

// ---------------- GEMM: out[m][n] = relu(sum_k A[m][k]*W[n][k] + b[n]) ----------------
// A: bf16 [NN][KP], Wb: bf16 [NPAD][KP]. Block = 4 waves, one 16-row M-tile per block,
// wave w covers N-tiles w*5 .. w*5+4 (tile 19 skipped).

__global__ __launch_bounds__(256) void gemm_bias_relu(const __bf16* __restrict__ A,
                                                      const __bf16* __restrict__ Wb,
                                                      const float* __restrict__ bias,
                                                      float* __restrict__ out) {
    int mtile = blockIdx.x;
    int w = threadIdx.x >> 6;
    int lane = threadIdx.x & 63;
    int r = lane & 15;    // A row-in-tile / B col / D col
    int q = lane >> 4;    // k-block select / D row-block

    f32x4 acc[5] = {};
    const __bf16* Abase = A + (size_t)(mtile * 16 + r) * KP + q * 8;
    const __bf16* Bbase = Wb + (size_t)r * KP + q * 8;

    for (int ks = 0; ks < 10; ++ks) {
        bf16x8 af = *(const bf16x8*)(Abase + ks * 32);
#pragma unroll
        for (int t = 0; t < 5; ++t) {
            int tn = w * 5 + t;
            if (tn < NTILES) {
                bf16x8 bfr = *(const bf16x8*)(Bbase + (size_t)tn * 16 * KP + ks * 32);
                acc[t] = __builtin_amdgcn_mfma_f32_16x16x32_bf16(af, bfr, acc[t], 0, 0, 0);
            }
        }
    }

#pragma unroll
    for (int t = 0; t < 5; ++t) {
        int tn = w * 5 + t;
        if (tn >= NTILES) continue;
        int n = tn * 16 + r;
        if (n >= DD) continue;
        float bv = bias[n];
#pragma unroll
        for (int j = 0; j < 4; ++j) {
            int m = mtile * 16 + q * 4 + j;
            float v = acc[t][j] + bv;
            out[(size_t)m * DD + n] = v > 0.f ? v : 0.f;
        }
    }
}

// ---------------- launch ----------------

extern "C" void kernel_launch(void* const* d_in, const int* in_sizes, int n_in,
                              void* d_out, int out_size, void* d_ws, size_t ws_size,
                              hipStream_t stream) {
    const float* features = (const float*)d_in[0];
    const int*   src      = (const int*)d_in[1];
    const int*   dst      = (const int*)d_in[2];
    const float* W1       = (const float*)d_in[3];
    const float* b1       = (const float*)d_in[4];
    const float* W2       = (const float*)d_in[5];
    const float* b2       = (const float*)d_in[6];
    float* out = (float*)d_out;

    char* ws = (char*)d_ws;
    size_t off = 0;
    auto alloc = [&](size_t bytes) -> void* {
        void* p = ws + off;
        off += (bytes + 255) & ~(size_t)255;
        return p;
    };
    int*    offsets = (int*)alloc((NN + 1) * sizeof(int));
    int*    cursor  = (int*)alloc(NN * sizeof(int));      // doubles as counts
    int*    esrc    = (int*)alloc(NE * sizeof(int));
    __bf16* W1b     = (__bf16*)alloc((size_t)NPAD * KP * sizeof(__bf16));
    __bf16* W2b     = (__bf16*)alloc((size_t)NPAD * KP * sizeof(__bf16));
    __bf16* aggb    = (__bf16*)alloc((size_t)NN * KP * sizeof(__bf16));
    float*  h1      = (float*)alloc((size_t)NN * DD * sizeof(float));
    (void)ws_size; (void)in_sizes; (void)n_in; (void)out_size;

    int* counts = cursor;

    hipLaunchKernelGGL(zero_i32, dim3(40), dim3(256), 0, stream, counts, NN);
    hipLaunchKernelGGL(hist_kernel, dim3((NE + 255) / 256), dim3(256), 0, stream, dst, counts);
    hipLaunchKernelGGL(scan_kernel, dim3(1), dim3(1024), 0, stream, counts, offsets);
    hipLaunchKernelGGL(copy_i32, dim3(40), dim3(256), 0, stream, offsets, cursor, NN);
    hipLaunchKernelGGL(scatter_kernel, dim3((NE + 255) / 256), dim3(256), 0, stream, src, dst, cursor, esrc);
    hipLaunchKernelGGL(convw_kernel, dim3((NPAD * KP + 255) / 256), dim3(256), 0, stream, W1, W1b);
    hipLaunchKernelGGL(convw_kernel, dim3((NPAD * KP + 255) / 256), dim3(256), 0, stream, W2, W2b);

    // layer 1
    hipLaunchKernelGGL(agg_kernel, dim3(NN / 4), dim3(256), 0, stream, features, aggb, offsets, esrc);
    hipLaunchKernelGGL(gemm_bias_relu, dim3(NN / 16), dim3(256), 0, stream, aggb, W1b, b1, h1);
    // layer 2
    hipLaunchKernelGGL(agg_kernel, dim3(NN / 4), dim3(256), 0, stream, h1, aggb, offsets, esrc);
    hipLaunchKernelGGL(gemm_bias_relu, dim3(NN / 16), dim3(256), 0, stream, aggb, W2b, b2, out);
}

// Round 2
// 129.316 us; speedup vs baseline: 1.6017x; 1.6017x over previous
//
#include <hip/hip_runtime.h>
#include <hip/hip_bf16.h>
#include <cstdint>
#include <cstddef>

#define NN 10000
#define NE 160000
#define DD 300
#define KP 320      // K padded to 10 MFMA steps of 32
#define NPAD 304    // N (W rows) padded to 19 tiles of 16
#define NTILES 19
#define MTILES 625  // NN/16

using bf16x8 = __attribute__((ext_vector_type(8))) __bf16;
using bf16x4 = __attribute__((ext_vector_type(4))) __bf16;
using f32x4  = __attribute__((ext_vector_type(4))) float;

// ---------------- CSR build ----------------

__global__ void zero_i32(int* p, int n) {
    int i = blockIdx.x * 256 + threadIdx.x;
    if (i < n) p[i] = 0;
}

__global__ void hist_kernel(const int* __restrict__ dst, int* __restrict__ counts) {
    int e = blockIdx.x * 256 + threadIdx.x;
    if (e < NE) atomicAdd(&counts[dst[e]], 1);
}

// single-block exclusive scan over NN counts -> offsets[NN+1], also copies to cursor
__global__ __launch_bounds__(1024) void scan_kernel(const int* __restrict__ counts,
                                                    int* __restrict__ offsets,
                                                    int* __restrict__ cursor) {
    __shared__ int wsum[16];
    __shared__ int carry_s;
    const int lane = threadIdx.x & 63;
    const int wv = threadIdx.x >> 6;
    if (threadIdx.x == 0) carry_s = 0;
    __syncthreads();
    for (int base = 0; base < NN; base += 1024) {
        int i = base + (int)threadIdx.x;
        int x = (i < NN) ? counts[i] : 0;
        // wave inclusive scan (no barriers)
        int s = x;
#pragma unroll
        for (int off = 1; off < 64; off <<= 1) {
            int v = __shfl_up(s, off);
            if (lane >= off) s += v;
        }
        if (lane == 63) wsum[wv] = s;
        __syncthreads();
        int wpre = 0;
#pragma unroll
        for (int k = 0; k < 16; ++k) {
            int v = wsum[k];
            wpre += (k < wv) ? v : 0;
        }
        int carry = carry_s;
        __syncthreads();
        int incl = carry + wpre + s;
        int excl = incl - x;
        if (i < NN) { offsets[i] = excl; cursor[i] = excl; }
        else if (i == NN) { offsets[NN] = excl; }
        if (threadIdx.x == 1023) carry_s = incl;
        // next iteration's first __syncthreads orders carry_s write vs reads
    }
}

__global__ void scatter_kernel(const int* __restrict__ src, const int* __restrict__ dst,
                               int* __restrict__ cursor, int* __restrict__ esrc) {
    int e = blockIdx.x * 256 + threadIdx.x;
    if (e < NE) {
        int pos = atomicAdd(&cursor[dst[e]], 1);
        esrc[pos] = src[e];
    }
}

// ---------------- W1,W2 -> bf16 padded [NPAD][KP] ----------------

__global__ void convw_kernel(const float* __restrict__ W1, const float* __restrict__ W2,
                             __bf16* __restrict__ W1b, __bf16* __restrict__ W2b) {
    int idx = blockIdx.x * 256 + threadIdx.x;
    if (idx >= NPAD * KP) return;
    int n = idx / KP;
    int k = idx - n * KP;
    bool v = (n < DD && k < DD);
    W1b[idx] = (__bf16)(v ? W1[n * DD + k] : 0.f);
    W2b[idx] = (__bf16)(v ? W2[n * DD + k] : 0.f);
}

// ---------------- aggregation: wave per node, broadcast edge indices, f32x4 gather ----------------

__global__ __launch_bounds__(256) void agg_kernel(const float* __restrict__ h,
                                                  __bf16* __restrict__ agg,
                                                  const int* __restrict__ offsets,
                                                  const int* __restrict__ esrc) {
    const int node = (int)((blockIdx.x * 256 + threadIdx.x) >> 6);
    const int lane = threadIdx.x & 63;
    if (node >= NN) return;
    const bool hi = lane < 11;  // chunk 64+lane < 75  (300 floats = 75 f32x4)

    const f32x4* self4 = (const f32x4*)(h + (size_t)node * DD);
    f32x4 a0 = self4[lane];
    f32x4 a1 = hi ? self4[64 + lane] : (f32x4){0.f, 0.f, 0.f, 0.f};

    const int p0 = offsets[node], p1 = offsets[node + 1];
    for (int base = p0; base < p1; base += 64) {
        int cnt = min(64, p1 - base);
        int idx = 0;
        if (lane < cnt) idx = esrc[base + lane];
        for (int j = 0; j < cnt; ++j) {
            int nb = __shfl(idx, j);
            const f32x4* r4 = (const f32x4*)(h + (size_t)nb * DD);
            a0 += r4[lane];
            if (hi) a1 += r4[64 + lane];
        }
    }

    // write bf16 padded row [KP]
    __bf16* o = agg + (size_t)node * KP;
    if (lane < 75) {
        bf16x4 v;
        v[0] = (__bf16)a0[0]; v[1] = (__bf16)a0[1];
        v[2] = (__bf16)a0[2]; v[3] = (__bf16)a0[3];
        *(bf16x4*)(o + 4 * lane) = v;
    } else if (lane < 80) {
        bf16x4 z = {};
        *(bf16x4*)(o + 4 * lane) = z;   // pad cols 300..319
    }
    if (hi) {
        bf16x4 v;
        v[0] = (__bf16)a1[0]; v[1] = (__bf16)a1[1];
        v[2] = (__bf16)a1[2]; v[3] = (__bf16)a1[3];
        *(bf16x4*)(o + 4 * (64 + lane)) = v;
    }
}

// ---------------- GEMM: out[m][n] = relu(sum_k A[m][k]*W[n][k] + b[n]) ----------------
// W-stationary: wave w holds B frags for N-tiles w*5..w*5+4 in registers (200 VGPR),
// grid-strides over M-tiles loading only A fragments. grid=256 -> 1 block/CU.

__global__ __launch_bounds__(256, 1) void gemm_bias_relu(const __bf16* __restrict__ A,
                                                         const __bf16* __restrict__ Wb,
                                                         const float* __restrict__ bias,
                                                         float* __restrict__ out) {
    const int w = threadIdx.x >> 6;
    const int lane = threadIdx.x & 63;
    const int r = lane & 15;    // A row-in-tile / B col / D col
    const int q = lane >> 4;    // k-block select / D row-block

    // preload B fragments (register-stationary) + bias
    bf16x8 b[5][10];
    float bv[5];
    const __bf16* Bb = Wb + (size_t)r * KP + q * 8;
#pragma unroll
    for (int t = 0; t < 5; ++t) {
        const int tn = w * 5 + t;
        const bool valid = tn < NTILES;
        const __bf16* Bt = Bb + (size_t)(valid ? tn : 0) * 16 * KP;
#pragma unroll
        for (int ks = 0; ks < 10; ++ks)
            b[t][ks] = *(const bf16x8*)(Bt + ks * 32);
        const int n = tn * 16 + r;
        bv[t] = (valid && n < DD) ? bias[n] : 0.f;
    }

    for (int mt = blockIdx.x; mt < MTILES; mt += gridDim.x) {
        const __bf16* Ab = A + (size_t)(mt * 16 + r) * KP + q * 8;
        f32x4 acc[5] = {};
#pragma unroll
        for (int ks = 0; ks < 10; ++ks) {
            bf16x8 af = *(const bf16x8*)(Ab + ks * 32);
#pragma unroll
            for (int t = 0; t < 5; ++t)
                acc[t] = __builtin_amdgcn_mfma_f32_16x16x32_bf16(af, b[t][ks], acc[t], 0, 0, 0);
        }
#pragma unroll
        for (int t = 0; t < 5; ++t) {
            const int n = (w * 5 + t) * 16 + r;
            if (n < DD) {
#pragma unroll
                for (int j = 0; j < 4; ++j) {
                    const int m = mt * 16 + q * 4 + j;
                    float v = acc[t][j] + bv[t];
                    out[(size_t)m * DD + n] = v > 0.f ? v : 0.f;
                }
            }
        }
    }
}

// ---------------- launch ----------------

extern "C" void kernel_launch(void* const* d_in, const int* in_sizes, int n_in,
                              void* d_out, int out_size, void* d_ws, size_t ws_size,
                              hipStream_t stream) {
    const float* features = (const float*)d_in[0];
    const int*   src      = (const int*)d_in[1];
    const int*   dst      = (const int*)d_in[2];
    const float* W1       = (const float*)d_in[3];
    const float* b1       = (const float*)d_in[4];
    const float* W2       = (const float*)d_in[5];
    const float* b2       = (const float*)d_in[6];
    float* out = (float*)d_out;

    char* ws = (char*)d_ws;
    size_t off = 0;
    auto alloc = [&](size_t bytes) -> void* {
        void* p = ws + off;
        off += (bytes + 255) & ~(size_t)255;
        return p;
    };
    int*    offsets = (int*)alloc((NN + 1) * sizeof(int));
    int*    cursor  = (int*)alloc(NN * sizeof(int));      // doubles as counts
    int*    esrc    = (int*)alloc(NE * sizeof(int));
    __bf16* W1b     = (__bf16*)alloc((size_t)NPAD * KP * sizeof(__bf16));
    __bf16* W2b     = (__bf16*)alloc((size_t)NPAD * KP * sizeof(__bf16));
    __bf16* aggb    = (__bf16*)alloc((size_t)NN * KP * sizeof(__bf16));
    float*  h1      = (float*)alloc((size_t)NN * DD * sizeof(float));
    (void)ws_size; (void)in_sizes; (void)n_in; (void)out_size;

    int* counts = cursor;

    hipLaunchKernelGGL(zero_i32, dim3(40), dim3(256), 0, stream, counts, NN);
    hipLaunchKernelGGL(hist_kernel, dim3((NE + 255) / 256), dim3(256), 0, stream, dst, counts);
    hipLaunchKernelGGL(scan_kernel, dim3(1), dim3(1024), 0, stream, counts, offsets, cursor);
    hipLaunchKernelGGL(scatter_kernel, dim3((NE + 255) / 256), dim3(256), 0, stream, src, dst, cursor, esrc);
    hipLaunchKernelGGL(convw_kernel, dim3((NPAD * KP + 255) / 256), dim3(256), 0, stream, W1, W2, W1b, W2b);

    // layer 1
    hipLaunchKernelGGL(agg_kernel, dim3(NN / 4), dim3(256), 0, stream, features, aggb, offsets, esrc);
    hipLaunchKernelGGL(gemm_bias_relu, dim3(256), dim3(256), 0, stream, aggb, W1b, b1, h1);
    // layer 2
    hipLaunchKernelGGL(agg_kernel, dim3(NN / 4), dim3(256), 0, stream, h1, aggb, offsets, esrc);
    hipLaunchKernelGGL(gemm_bias_relu, dim3(256), dim3(256), 0, stream, aggb, W2b, b2, out);
}

// Round 3
// 117.341 us; speedup vs baseline: 1.7652x; 1.1021x over previous
//
#include <hip/hip_runtime.h>
#include <hip/hip_bf16.h>
#include <cstdint>
#include <cstddef>

#define NN 10000
#define NE 160000
#define DD 300
#define KP 320      // K padded to 10 MFMA steps of 32
#define NPAD 320    // W rows padded to 20 tiles of 16
#define MTILES 625  // NN/16

using bf16x8 = __attribute__((ext_vector_type(8))) __bf16;
using f32x4  = __attribute__((ext_vector_type(4))) float;

// ---------------- CSR build ----------------

__global__ void zero_i32(int* p, int n) {
    int i = blockIdx.x * 256 + threadIdx.x;
    if (i < n) p[i] = 0;
}

__global__ void hist_kernel(const int* __restrict__ dst, int* __restrict__ counts) {
    int e = blockIdx.x * 256 + threadIdx.x;
    if (e < NE) atomicAdd(&counts[dst[e]], 1);
}

// single-block exclusive scan over NN counts -> offsets[NN+1], also copies to cursor
__global__ __launch_bounds__(1024) void scan_kernel(const int* __restrict__ counts,
                                                    int* __restrict__ offsets,
                                                    int* __restrict__ cursor) {
    __shared__ int wsum[16];
    __shared__ int carry_s;
    const int lane = threadIdx.x & 63;
    const int wv = threadIdx.x >> 6;
    if (threadIdx.x == 0) carry_s = 0;
    __syncthreads();
    for (int base = 0; base < NN; base += 1024) {
        int i = base + (int)threadIdx.x;
        int x = (i < NN) ? counts[i] : 0;
        int s = x;
#pragma unroll
        for (int off = 1; off < 64; off <<= 1) {
            int v = __shfl_up(s, off);
            if (lane >= off) s += v;
        }
        if (lane == 63) wsum[wv] = s;
        __syncthreads();
        int wpre = 0;
#pragma unroll
        for (int k = 0; k < 16; ++k) {
            int v = wsum[k];
            wpre += (k < wv) ? v : 0;
        }
        int carry = carry_s;
        __syncthreads();
        int incl = carry + wpre + s;
        int excl = incl - x;
        if (i < NN) { offsets[i] = excl; cursor[i] = excl; }
        else if (i == NN) { offsets[NN] = excl; }
        if (threadIdx.x == 1023) carry_s = incl;
    }
}

__global__ void scatter_kernel(const int* __restrict__ src, const int* __restrict__ dst,
                               int* __restrict__ cursor, int* __restrict__ esrc) {
    int e = blockIdx.x * 256 + threadIdx.x;
    if (e < NE) {
        int pos = atomicAdd(&cursor[dst[e]], 1);
        esrc[pos] = src[e];
    }
}

// ---------------- prep: W1,W2 -> bf16 [NPAD][KP]; features -> bf16 [NN][KP] ----------------

__global__ void prep_kernel(const float* __restrict__ W1, const float* __restrict__ W2,
                            const float* __restrict__ feat,
                            __bf16* __restrict__ W1b, __bf16* __restrict__ W2b,
                            __bf16* __restrict__ fb) {
    int idx = blockIdx.x * 256 + threadIdx.x;
    if (idx < NPAD * KP) {
        int n = idx / KP;
        int k = idx - n * KP;
        bool v = (n < DD && k < DD);
        W1b[idx] = (__bf16)(v ? W1[n * DD + k] : 0.f);
        W2b[idx] = (__bf16)(v ? W2[n * DD + k] : 0.f);
    }
    int fidx = idx - NPAD * KP;
    if (fidx >= 0 && fidx < NN * KP) {
        int n = fidx / KP;
        int k = fidx - n * KP;
        fb[fidx] = (__bf16)((k < DD) ? feat[n * DD + k] : 0.f);
    }
}

// ---------------- aggregation: wave per node, bf16 gather (one dwordx4/neighbor/lane) ----------------

__global__ __launch_bounds__(256) void agg_kernel(const __bf16* __restrict__ h,   // [NN][KP]
                                                  __bf16* __restrict__ agg,       // [NN][KP]
                                                  const int* __restrict__ offsets,
                                                  const int* __restrict__ esrc) {
    const int node = (int)((blockIdx.x * 256 + threadIdx.x) >> 6);
    const int lane = threadIdx.x & 63;
    if (node >= NN) return;
    const bool act = lane < (KP / 8);   // 40 lanes x 8 bf16 = 320 cols

    const uint4* hv = (const uint4*)h;  // row stride KP/8 = 40
    float acc[8] = {0.f, 0.f, 0.f, 0.f, 0.f, 0.f, 0.f, 0.f};

    auto addrow = [&](int row) {
        uint4 v = hv[(size_t)row * (KP / 8) + lane];
        uint32_t u[4] = {v.x, v.y, v.z, v.w};
#pragma unroll
        for (int i = 0; i < 4; ++i) {
            acc[2 * i]     += __uint_as_float(u[i] << 16);
            acc[2 * i + 1] += __uint_as_float(u[i] & 0xffff0000u);
        }
    };

    if (act) addrow(node);   // self-loop

    const int p0 = offsets[node], p1 = offsets[node + 1];
    for (int base = p0; base < p1; base += 64) {
        int cnt = min(64, p1 - base);
        int idx = 0;
        if (lane < cnt) idx = esrc[base + lane];
        for (int j = 0; j < cnt; ++j) {
            int nb = __shfl(idx, j);
            if (act) addrow(nb);
        }
    }

    if (act) {
        bf16x8 v;
#pragma unroll
        for (int i = 0; i < 8; ++i) v[i] = (__bf16)acc[i];
        *(bf16x8*)(agg + (size_t)node * KP + 8 * lane) = v;
    }
}

// ---------------- GEMM: out[m][n] = relu(sum_k A[m][k]*W[n][k] + b[n]) ----------------
// W-stationary: wave w holds B frags for N-tiles w*5..w*5+4 in registers (200 VGPR),
// grid-strides over M-tiles. BF16OUT: write bf16 [NN][KP] (all 320 cols, pads get 0);
// else f32 [NN][DD].

template <bool BF16OUT>
__global__ __launch_bounds__(256, 1) void gemm_bias_relu(const __bf16* __restrict__ A,
                                                         const __bf16* __restrict__ Wb,
                                                         const float* __restrict__ bias,
                                                         void* __restrict__ outp) {
    const int w = threadIdx.x >> 6;
    const int lane = threadIdx.x & 63;
    const int r = lane & 15;    // A row-in-tile / B col / D col
    const int q = lane >> 4;    // k-block select / D row-block

    bf16x8 b[5][10];
    float bv[5];
    const __bf16* Bb = Wb + (size_t)r * KP + q * 8;
#pragma unroll
    for (int t = 0; t < 5; ++t) {
        const int tn = w * 5 + t;
        const __bf16* Bt = Bb + (size_t)tn * 16 * KP;
#pragma unroll
        for (int ks = 0; ks < 10; ++ks)
            b[t][ks] = *(const bf16x8*)(Bt + ks * 32);
        const int n = tn * 16 + r;
        bv[t] = (n < DD) ? bias[n] : 0.f;
    }

    for (int mt = blockIdx.x; mt < MTILES; mt += gridDim.x) {
        const __bf16* Ab = A + (size_t)(mt * 16 + r) * KP + q * 8;
        f32x4 acc[5] = {};
#pragma unroll
        for (int ks = 0; ks < 10; ++ks) {
            bf16x8 af = *(const bf16x8*)(Ab + ks * 32);
#pragma unroll
            for (int t = 0; t < 5; ++t)
                acc[t] = __builtin_amdgcn_mfma_f32_16x16x32_bf16(af, b[t][ks], acc[t], 0, 0, 0);
        }
#pragma unroll
        for (int t = 0; t < 5; ++t) {
            const int n = (w * 5 + t) * 16 + r;
#pragma unroll
            for (int j = 0; j < 4; ++j) {
                const int m = mt * 16 + q * 4 + j;
                float v = acc[t][j] + bv[t];
                v = v > 0.f ? v : 0.f;
                if (BF16OUT) {
                    ((__bf16*)outp)[(size_t)m * KP + n] = (__bf16)v;
                } else if (n < DD) {
                    ((float*)outp)[(size_t)m * DD + n] = v;
                }
            }
        }
    }
}

// ---------------- launch ----------------

extern "C" void kernel_launch(void* const* d_in, const int* in_sizes, int n_in,
                              void* d_out, int out_size, void* d_ws, size_t ws_size,
                              hipStream_t stream) {
    const float* features = (const float*)d_in[0];
    const int*   src      = (const int*)d_in[1];
    const int*   dst      = (const int*)d_in[2];
    const float* W1       = (const float*)d_in[3];
    const float* b1       = (const float*)d_in[4];
    const float* W2       = (const float*)d_in[5];
    const float* b2       = (const float*)d_in[6];
    float* out = (float*)d_out;

    char* ws = (char*)d_ws;
    size_t off = 0;
    auto alloc = [&](size_t bytes) -> void* {
        void* p = ws + off;
        off += (bytes + 255) & ~(size_t)255;
        return p;
    };
    int*    offsets = (int*)alloc((NN + 1) * sizeof(int));
    int*    cursor  = (int*)alloc(NN * sizeof(int));      // doubles as counts
    int*    esrc    = (int*)alloc(NE * sizeof(int));
    __bf16* W1b     = (__bf16*)alloc((size_t)NPAD * KP * sizeof(__bf16));
    __bf16* W2b     = (__bf16*)alloc((size_t)NPAD * KP * sizeof(__bf16));
    __bf16* fb      = (__bf16*)alloc((size_t)NN * KP * sizeof(__bf16));
    __bf16* aggb    = (__bf16*)alloc((size_t)NN * KP * sizeof(__bf16));
    __bf16* h1b     = (__bf16*)alloc((size_t)NN * KP * sizeof(__bf16));
    (void)ws_size; (void)in_sizes; (void)n_in; (void)out_size;

    int* counts = cursor;

    hipLaunchKernelGGL(zero_i32, dim3(40), dim3(256), 0, stream, counts, NN);
    hipLaunchKernelGGL(hist_kernel, dim3((NE + 255) / 256), dim3(256), 0, stream, dst, counts);
    hipLaunchKernelGGL(scan_kernel, dim3(1), dim3(1024), 0, stream, counts, offsets, cursor);
    hipLaunchKernelGGL(scatter_kernel, dim3((NE + 255) / 256), dim3(256), 0, stream, src, dst, cursor, esrc);
    hipLaunchKernelGGL(prep_kernel, dim3((NPAD * KP + NN * KP + 255) / 256), dim3(256), 0, stream,
                       W1, W2, features, W1b, W2b, fb);

    // layer 1
    hipLaunchKernelGGL(agg_kernel, dim3(NN / 4), dim3(256), 0, stream, fb, aggb, offsets, esrc);
    hipLaunchKernelGGL((gemm_bias_relu<true>), dim3(256), dim3(256), 0, stream, aggb, W1b, b1, (void*)h1b);
    // layer 2
    hipLaunchKernelGGL(agg_kernel, dim3(NN / 4), dim3(256), 0, stream, h1b, aggb, offsets, esrc);
    hipLaunchKernelGGL((gemm_bias_relu<false>), dim3(256), dim3(256), 0, stream, aggb, W2b, b2, (void*)out);
}